// Round 1
// baseline (970.941 us; speedup 1.0000x reference)
//
#include <hip/hip_runtime.h>
#include <math.h>

#define B_ 4
#define S_ 2048
#define D_ 1024
#define F_ 4096
#define E_ 8
#define T_ 8192
#define LBW_ 0.01f
#define HROWS_ 17408  // capacity for sum of per-expert 128-padded counts (<= 2T + 8*127, rounded up)

typedef unsigned short u16;
typedef __attribute__((ext_vector_type(8))) short bf16x8;
typedef __attribute__((ext_vector_type(4))) float f32x4;

__device__ __forceinline__ u16 f2b(float f) {
    unsigned u = __float_as_uint(f);
    u = (u + 0x7FFFu + ((u >> 16) & 1u)) >> 16;   // RNE f32 -> bf16
    return (u16)u;
}
__device__ __forceinline__ float gelu_f(float v) {
    return 0.5f * v * (1.0f + erff(v * 0.70710678118654752440f));
}

// ---------------- x -> bf16 ----------------
__global__ __launch_bounds__(256) void cvt_x_kernel(const float* __restrict__ x,
                                                    u16* __restrict__ xb) {
    size_t i = ((size_t)blockIdx.x * 256 + threadIdx.x) * 4;
    float4 v = *(const float4*)(x + i);
    uint2 r;
    r.x = (unsigned)f2b(v.x) | ((unsigned)f2b(v.y) << 16);
    r.y = (unsigned)f2b(v.z) | ((unsigned)f2b(v.w) << 16);
    *(uint2*)(xb + i) = r;
}

// ------- per-expert transpose + convert: src (R x C f32, row-major) -> dst (C x R bf16) -------
__global__ __launch_bounds__(256) void cvt_T_kernel(const float* __restrict__ src,
                                                    u16* __restrict__ dst, int R, int C) {
    __shared__ u16 t[64][72];
    const int e = blockIdx.z;
    const float* s = src + (size_t)e * R * C;
    u16* d = dst + (size_t)e * R * C;
    const int r0 = blockIdx.y * 64, c0 = blockIdx.x * 64;
    const int tid = threadIdx.x;
    {
        int rr = tid >> 2, cq = (tid & 3) * 16;
        #pragma unroll
        for (int j = 0; j < 16; j += 4) {
            float4 v = *(const float4*)(s + (size_t)(r0 + rr) * C + c0 + cq + j);
            t[cq + j + 0][rr] = f2b(v.x);
            t[cq + j + 1][rr] = f2b(v.y);
            t[cq + j + 2][rr] = f2b(v.z);
            t[cq + j + 3][rr] = f2b(v.w);
        }
    }
    __syncthreads();
    {
        int cr = tid >> 2, rq = (tid & 3) * 16;
        #pragma unroll
        for (int j = 0; j < 16; j += 8) {
            int4 pk; u16* pw = (u16*)&pk;
            #pragma unroll
            for (int jj = 0; jj < 8; ++jj) pw[jj] = t[cr][rq + j + jj];
            *(int4*)(d + (size_t)(c0 + cr) * R + r0 + rq + j) = pk;
        }
    }
}

// ---------------- gate: logits (f64), softmax, top-2, routing lists, loss partials ----------------
__global__ __launch_bounds__(64) void gate_kernel(
    const float* __restrict__ x, const float* __restrict__ ew,
    const float* __restrict__ gw, const float* __restrict__ gb,
    float* __restrict__ combine, int* __restrict__ idx, int* __restrict__ cnt,
    int* __restrict__ fcnt, float* __restrict__ psum)
{
    const int t = blockIdx.x, l = threadIdx.x;
    const float* xr = x + (size_t)t * D_;
    double acc[E_];
    #pragma unroll
    for (int e = 0; e < E_; ++e) acc[e] = 0.0;
    #pragma unroll
    for (int kk = 0; kk < 16; kk += 4) {
        float4 xv = *(const float4*)(xr + l * 16 + kk);
        float xs[4] = {xv.x, xv.y, xv.z, xv.w};
        #pragma unroll
        for (int j = 0; j < 4; ++j) {
            const float* gr = gw + (size_t)(l * 16 + kk + j) * E_;
            float4 g0 = *(const float4*)(gr);
            float4 g1 = *(const float4*)(gr + 4);
            acc[0] += (double)xs[j] * g0.x;  acc[1] += (double)xs[j] * g0.y;
            acc[2] += (double)xs[j] * g0.z;  acc[3] += (double)xs[j] * g0.w;
            acc[4] += (double)xs[j] * g1.x;  acc[5] += (double)xs[j] * g1.y;
            acc[6] += (double)xs[j] * g1.z;  acc[7] += (double)xs[j] * g1.w;
        }
    }
    #pragma unroll
    for (int e = 0; e < E_; ++e) {
        #pragma unroll
        for (int m = 32; m > 0; m >>= 1) acc[e] += __shfl_xor(acc[e], m);
    }
    if (l == 0) {
        const int b = t / S_;
        double p[E_]; double mx = -1e300;
        #pragma unroll
        for (int e = 0; e < E_; ++e) {
            p[e] = acc[e] + (double)gb[e] + (double)ew[b * E_ + e];
            mx = fmax(mx, p[e]);
        }
        double s = 0.0;
        #pragma unroll
        for (int e = 0; e < E_; ++e) { p[e] = exp(p[e] - mx); s += p[e]; }
        double inv = 1.0 / s;
        #pragma unroll
        for (int e = 0; e < E_; ++e) p[e] *= inv;
        double m1 = -1.0; int e1 = 0;
        #pragma unroll
        for (int e = 0; e < E_; ++e) if (p[e] > m1) { m1 = p[e]; e1 = e; }
        double m2 = -1.0; int e2 = 0;
        #pragma unroll
        for (int e = 0; e < E_; ++e) if (e != e1 && p[e] > m2) { m2 = p[e]; e2 = e; }
        float c1 = (float)(m1 / (m1 + m2)), c2 = (float)(m2 / (m1 + m2));
        #pragma unroll
        for (int e = 0; e < E_; ++e)
            combine[t * E_ + e] = (e == e1) ? c1 : ((e == e2) ? c2 : 0.0f);
        int q1 = atomicAdd(&cnt[e1], 1); idx[e1 * T_ + q1] = t;
        int q2 = atomicAdd(&cnt[e2], 1); idx[e2 * T_ + q2] = t;
        atomicAdd(&fcnt[(t & 63) * E_ + e1], 1);
        #pragma unroll
        for (int e = 0; e < E_; ++e) atomicAdd(&psum[(t & 63) * E_ + e], (float)p[e]);
    }
}

__global__ void offsets_kernel(const int* __restrict__ cnt, int* __restrict__ off) {
    if (threadIdx.x == 0 && blockIdx.x == 0) {
        int o = 0;
        for (int e = 0; e < E_; ++e) { off[e] = o; o += ((cnt[e] + 127) >> 7) << 7; }
    }
}

// ---------------- GEMM1: h[slot, f] = gelu(x[tok] @ w1[e] + b1[e]), bf16 out ----------------
__global__ __launch_bounds__(256) void gemm1_kernel(
    const u16* __restrict__ xb, const u16* __restrict__ w1t,
    const float* __restrict__ b1, const int* __restrict__ idxAll,
    const int* __restrict__ cntAll, const int* __restrict__ off,
    u16* __restrict__ h)
{
    const int e = blockIdx.z;
    const int cnt = cntAll[e];
    const int tm = blockIdx.y, tn = blockIdx.x;
    if (tm * 128 >= cnt) return;
    const int base = off[e];
    const int* idx_e = idxAll + e * T_;
    const u16* Bsrc = w1t + (size_t)e * D_ * F_;   // [F][D] bf16

    __shared__ __align__(16) u16 As[128 * 64];
    __shared__ __align__(16) u16 Bs[128 * 64];
    char* Ab = (char*)As; char* Bb = (char*)Bs;
    const int tid = threadIdx.x;
    const int l = tid & 63, wid = tid >> 6;
    const int wm = (wid >> 1) * 64, wn = (wid & 1) * 64;
    const int lr = l & 15, lg = l >> 4;

    f32x4 acc[4][4];
    #pragma unroll
    for (int mi = 0; mi < 4; ++mi)
        #pragma unroll
        for (int ni = 0; ni < 4; ++ni)
            acc[mi][ni] = (f32x4){0.f, 0.f, 0.f, 0.f};

    const int srow = tid >> 3, skc = tid & 7;
    const u16* aptr[4]; const u16* bptr[4]; int wof[4];
    #pragma unroll
    for (int it = 0; it < 4; ++it) {
        int row = it * 32 + srow;
        int r = tm * 128 + row;
        int tok = (r < cnt) ? idx_e[r] : 0;
        aptr[it] = xb + (size_t)tok * D_ + skc * 8;
        bptr[it] = Bsrc + (size_t)(tn * 128 + row) * D_ + skc * 8;
        wof[it] = row * 128 + ((skc * 16) ^ ((row & 7) << 4));
    }

    for (int k0 = 0; k0 < D_; k0 += 64) {
        #pragma unroll
        for (int it = 0; it < 4; ++it)
            *(int4*)(Ab + wof[it]) = *(const int4*)(aptr[it] + k0);
        #pragma unroll
        for (int it = 0; it < 4; ++it)
            *(int4*)(Bb + wof[it]) = *(const int4*)(bptr[it] + k0);
        __syncthreads();
        #pragma unroll
        for (int kb = 0; kb < 2; ++kb) {
            bf16x8 af[4], bfv[4];
            #pragma unroll
            for (int mi = 0; mi < 4; ++mi) {
                int row = wm + mi * 16 + lr;
                af[mi] = *(const bf16x8*)(Ab + row * 128 + ((kb * 64 + lg * 16) ^ ((row & 7) << 4)));
            }
            #pragma unroll
            for (int ni = 0; ni < 4; ++ni) {
                int col = wn + ni * 16 + lr;
                bfv[ni] = *(const bf16x8*)(Bb + col * 128 + ((kb * 64 + lg * 16) ^ ((col & 7) << 4)));
            }
            #pragma unroll
            for (int mi = 0; mi < 4; ++mi)
                #pragma unroll
                for (int ni = 0; ni < 4; ++ni)
                    acc[mi][ni] = __builtin_amdgcn_mfma_f32_16x16x32_bf16(af[mi], bfv[ni], acc[mi][ni], 0, 0, 0);
        }
        __syncthreads();
    }

    const float* b1e = b1 + e * F_;
    #pragma unroll
    for (int mi = 0; mi < 4; ++mi) {
        int rb = wm + mi * 16 + lg * 4;
        #pragma unroll
        for (int ni = 0; ni < 4; ++ni) {
            int f = tn * 128 + wn + ni * 16 + lr;
            float bias = b1e[f];
            #pragma unroll
            for (int j = 0; j < 4; ++j) {
                int slot = base + tm * 128 + rb + j;
                h[(size_t)slot * F_ + f] = f2b(gelu_f(acc[mi][ni][j] + bias));
            }
        }
    }
}

// ---------------- GEMM2: out[tok, d] += combine * (h @ w2[e] + b2[e]) ----------------
__global__ __launch_bounds__(256) void gemm2_kernel(
    const u16* __restrict__ h, const u16* __restrict__ w2t,
    const float* __restrict__ b2, const float* __restrict__ combine,
    const int* __restrict__ idxAll, const int* __restrict__ cntAll,
    const int* __restrict__ off, float* __restrict__ out)
{
    const int e = blockIdx.z;
    const int cnt = cntAll[e];
    const int tm = blockIdx.y, tn = blockIdx.x;
    if (tm * 128 >= cnt) return;
    const int base = off[e];
    const int* idx_e = idxAll + e * T_;
    const u16* Bsrc = w2t + (size_t)e * F_ * D_;   // [D][F] bf16

    __shared__ __align__(16) u16 As[128 * 64];
    __shared__ __align__(16) u16 Bs[128 * 64];
    char* Ab = (char*)As; char* Bb = (char*)Bs;
    const int tid = threadIdx.x;
    const int l = tid & 63, wid = tid >> 6;
    const int wm = (wid >> 1) * 64, wn = (wid & 1) * 64;
    const int lr = l & 15, lg = l >> 4;

    f32x4 acc[4][4];
    #pragma unroll
    for (int mi = 0; mi < 4; ++mi)
        #pragma unroll
        for (int ni = 0; ni < 4; ++ni)
            acc[mi][ni] = (f32x4){0.f, 0.f, 0.f, 0.f};

    const int srow = tid >> 3, skc = tid & 7;
    const u16* aptr[4]; const u16* bptr[4]; int wof[4];
    #pragma unroll
    for (int it = 0; it < 4; ++it) {
        int row = it * 32 + srow;
        aptr[it] = h + (size_t)(base + tm * 128 + row) * F_ + skc * 8;
        bptr[it] = Bsrc + (size_t)(tn * 128 + row) * F_ + skc * 8;
        wof[it] = row * 128 + ((skc * 16) ^ ((row & 7) << 4));
    }

    for (int k0 = 0; k0 < F_; k0 += 64) {
        #pragma unroll
        for (int it = 0; it < 4; ++it)
            *(int4*)(Ab + wof[it]) = *(const int4*)(aptr[it] + k0);
        #pragma unroll
        for (int it = 0; it < 4; ++it)
            *(int4*)(Bb + wof[it]) = *(const int4*)(bptr[it] + k0);
        __syncthreads();
        #pragma unroll
        for (int kb = 0; kb < 2; ++kb) {
            bf16x8 af[4], bfv[4];
            #pragma unroll
            for (int mi = 0; mi < 4; ++mi) {
                int row = wm + mi * 16 + lr;
                af[mi] = *(const bf16x8*)(Ab + row * 128 + ((kb * 64 + lg * 16) ^ ((row & 7) << 4)));
            }
            #pragma unroll
            for (int ni = 0; ni < 4; ++ni) {
                int col = wn + ni * 16 + lr;
                bfv[ni] = *(const bf16x8*)(Bb + col * 128 + ((kb * 64 + lg * 16) ^ ((col & 7) << 4)));
            }
            #pragma unroll
            for (int mi = 0; mi < 4; ++mi)
                #pragma unroll
                for (int ni = 0; ni < 4; ++ni)
                    acc[mi][ni] = __builtin_amdgcn_mfma_f32_16x16x32_bf16(af[mi], bfv[ni], acc[mi][ni], 0, 0, 0);
        }
        __syncthreads();
    }

    const float* b2e = b2 + e * D_;
    #pragma unroll
    for (int mi = 0; mi < 4; ++mi) {
        #pragma unroll
        for (int j = 0; j < 4; ++j) {
            int r = tm * 128 + wm + mi * 16 + lg * 4 + j;
            if (r < cnt) {
                int t = idx_e[r];
                float cw = combine[t * E_ + e];
                float* orow = out + (size_t)t * D_;
                #pragma unroll
                for (int ni = 0; ni < 4; ++ni) {
                    int d = tn * 128 + wn + ni * 16 + lr;
                    atomicAdd(&orow[d], cw * (acc[mi][ni][j] + b2e[d]));
                }
            }
        }
    }
}

__global__ void loss_kernel(const int* __restrict__ fcnt, const float* __restrict__ psum,
                            float* __restrict__ dst) {
    if (threadIdx.x == 0 && blockIdx.x == 0) {
        float loss = 0.f;
        for (int e = 0; e < E_; ++e) {
            float fs = 0.f, Ps = 0.f;
            for (int s = 0; s < 64; ++s) { fs += (float)fcnt[s * E_ + e]; Ps += psum[s * E_ + e]; }
            loss += (fs / (float)T_) * (Ps / (float)T_);
        }
        *dst = LBW_ * (float)E_ * loss;
    }
}

__global__ void sentinel_kernel(float* __restrict__ dst) {
    if (threadIdx.x == 0) dst[0] = -12345.0f;
}

extern "C" void kernel_launch(void* const* d_in, const int* in_sizes, int n_in,
                              void* d_out, int out_size, void* d_ws, size_t ws_size,
                              hipStream_t stream)
{
    const float* x  = (const float*)d_in[0];
    const float* ew = (const float*)d_in[1];
    const float* gw = (const float*)d_in[2];
    const float* gb = (const float*)d_in[3];
    const float* w1 = (const float*)d_in[4];
    const float* b1 = (const float*)d_in[5];
    const float* w2 = (const float*)d_in[6];
    const float* b2 = (const float*)d_in[7];
    float* out = (float*)d_out;

    char* ws = (char*)d_ws;
    size_t o = 0;
    u16* w1t = (u16*)(ws + o); o += (size_t)E_ * D_ * F_ * 2;
    u16* w2t = (u16*)(ws + o); o += (size_t)E_ * F_ * D_ * 2;
    u16* xb  = (u16*)(ws + o); o += (size_t)T_ * D_ * 2;
    u16* h   = (u16*)(ws + o); o += (size_t)HROWS_ * F_ * 2;
    float* combine = (float*)(ws + o); o += (size_t)T_ * E_ * 4;
    int* idx = (int*)(ws + o); o += (size_t)E_ * T_ * 4;
    size_t zoff = o;
    int* cnt   = (int*)(ws + o); o += 128;
    int* fcnt  = (int*)(ws + o); o += 64 * E_ * 4;
    float* psum = (float*)(ws + o); o += 64 * E_ * 4;
    int* off   = (int*)(ws + o); o += 128;
    const size_t ws_needed = o;

    if (ws_size < ws_needed) {
        // diagnosable failure: loss slot becomes -12345
        hipMemsetAsync(d_out, 0, (size_t)out_size * sizeof(float), stream);
        sentinel_kernel<<<1, 64, 0, stream>>>(out + (size_t)out_size - 1);
        return;
    }

    hipMemsetAsync(ws + zoff, 0, ws_needed - zoff, stream);
    hipMemsetAsync(d_out, 0, (size_t)out_size * sizeof(float), stream);

    cvt_x_kernel<<<T_ * D_ / 1024, 256, 0, stream>>>(x, xb);
    cvt_T_kernel<<<dim3(F_ / 64, D_ / 64, E_), 256, 0, stream>>>(w1, w1t, D_, F_);
    cvt_T_kernel<<<dim3(D_ / 64, F_ / 64, E_), 256, 0, stream>>>(w2, w2t, F_, D_);
    gate_kernel<<<T_, 64, 0, stream>>>(x, ew, gw, gb, combine, idx, cnt, fcnt, psum);
    offsets_kernel<<<1, 64, 0, stream>>>(cnt, off);
    gemm1_kernel<<<dim3(F_ / 128, T_ / 128, E_), 256, 0, stream>>>(xb, w1t, b1, idx, cnt, off, h);
    gemm2_kernel<<<dim3(D_ / 128, T_ / 128, E_), 256, 0, stream>>>(h, w2t, b2, combine, idx, cnt, off, out);
    loss_kernel<<<1, 64, 0, stream>>>(fcnt, psum, out + (size_t)out_size - 1);
}

// Round 2
// 970.804 us; speedup vs baseline: 1.0001x; 1.0001x over previous
//
#include <hip/hip_runtime.h>
#include <math.h>

#define B_ 4
#define S_ 2048
#define D_ 1024
#define F_ 4096
#define E_ 8
#define T_ 8192
#define LBW_ 0.01f
#define HROWS_ 17408  // capacity for sum of per-expert 128-padded counts

typedef unsigned short u16;
typedef __attribute__((ext_vector_type(8))) short bf16x8;
typedef __attribute__((ext_vector_type(4))) float f32x4;

// async global->LDS, 16B per lane; LDS dest = wave-uniform base + lane*16
#define GLOAD16(gp, lp) __builtin_amdgcn_global_load_lds( \
    (const __attribute__((address_space(1))) void*)(gp),  \
    (__attribute__((address_space(3))) void*)(lp), 16, 0, 0)

__device__ __forceinline__ u16 f2b(float f) {
    unsigned u = __float_as_uint(f);
    u = (u + 0x7FFFu + ((u >> 16) & 1u)) >> 16;   // RNE f32 -> bf16
    return (u16)u;
}
__device__ __forceinline__ float gelu_f(float v) {
    return 0.5f * v * (1.0f + erff(v * 0.70710678118654752440f));
}

// ------- per-expert transpose + convert: src (R x C f32, row-major) -> dst (C x R bf16) -------
__global__ __launch_bounds__(256) void cvt_T_kernel(const float* __restrict__ src,
                                                    u16* __restrict__ dst, int R, int C) {
    __shared__ u16 t[64][72];
    const int e = blockIdx.z;
    const float* s = src + (size_t)e * R * C;
    u16* d = dst + (size_t)e * R * C;
    const int r0 = blockIdx.y * 64, c0 = blockIdx.x * 64;
    const int tid = threadIdx.x;
    {
        int rr = tid >> 2, cq = (tid & 3) * 16;
        #pragma unroll
        for (int j = 0; j < 16; j += 4) {
            float4 v = *(const float4*)(s + (size_t)(r0 + rr) * C + c0 + cq + j);
            t[cq + j + 0][rr] = f2b(v.x);
            t[cq + j + 1][rr] = f2b(v.y);
            t[cq + j + 2][rr] = f2b(v.z);
            t[cq + j + 3][rr] = f2b(v.w);
        }
    }
    __syncthreads();
    {
        int cr = tid >> 2, rq = (tid & 3) * 16;
        #pragma unroll
        for (int j = 0; j < 16; j += 8) {
            int4 pk; u16* pw = (u16*)&pk;
            #pragma unroll
            for (int jj = 0; jj < 8; ++jj) pw[jj] = t[cr][rq + j + jj];
            *(int4*)(d + (size_t)(c0 + cr) * R + r0 + rq + j) = pk;
        }
    }
}

// ------- gate: logits (f64), softmax, top-2, routing lists, loss partials; also x->bf16 -------
__global__ __launch_bounds__(64) void gate_kernel(
    const float* __restrict__ x, const float* __restrict__ ew,
    const float* __restrict__ gw, const float* __restrict__ gb,
    u16* __restrict__ xb,
    float* __restrict__ combine, int* __restrict__ idx, int* __restrict__ cnt,
    int* __restrict__ fcnt, float* __restrict__ psum)
{
    const int t = blockIdx.x, l = threadIdx.x;
    const float* xr = x + (size_t)t * D_;
    double acc[E_];
    #pragma unroll
    for (int e = 0; e < E_; ++e) acc[e] = 0.0;
    u16 xw[16];
    #pragma unroll
    for (int kk = 0; kk < 16; kk += 4) {
        float4 xv = *(const float4*)(xr + l * 16 + kk);
        float xs[4] = {xv.x, xv.y, xv.z, xv.w};
        #pragma unroll
        for (int j = 0; j < 4; ++j) {
            xw[kk + j] = f2b(xs[j]);
            const float* gr = gw + (size_t)(l * 16 + kk + j) * E_;
            float4 g0 = *(const float4*)(gr);
            float4 g1 = *(const float4*)(gr + 4);
            acc[0] += (double)xs[j] * g0.x;  acc[1] += (double)xs[j] * g0.y;
            acc[2] += (double)xs[j] * g0.z;  acc[3] += (double)xs[j] * g0.w;
            acc[4] += (double)xs[j] * g1.x;  acc[5] += (double)xs[j] * g1.y;
            acc[6] += (double)xs[j] * g1.z;  acc[7] += (double)xs[j] * g1.w;
        }
    }
    *(int4*)(xb + (size_t)t * D_ + l * 16)     = *(int4*)(xw);
    *(int4*)(xb + (size_t)t * D_ + l * 16 + 8) = *(int4*)(xw + 8);
    #pragma unroll
    for (int e = 0; e < E_; ++e) {
        #pragma unroll
        for (int m = 32; m > 0; m >>= 1) acc[e] += __shfl_xor(acc[e], m);
    }
    if (l == 0) {
        const int b = t / S_;
        double p[E_]; double mx = -1e300;
        #pragma unroll
        for (int e = 0; e < E_; ++e) {
            p[e] = acc[e] + (double)gb[e] + (double)ew[b * E_ + e];
            mx = fmax(mx, p[e]);
        }
        double s = 0.0;
        #pragma unroll
        for (int e = 0; e < E_; ++e) { p[e] = exp(p[e] - mx); s += p[e]; }
        double inv = 1.0 / s;
        #pragma unroll
        for (int e = 0; e < E_; ++e) p[e] *= inv;
        double m1 = -1.0; int e1 = 0;
        #pragma unroll
        for (int e = 0; e < E_; ++e) if (p[e] > m1) { m1 = p[e]; e1 = e; }
        double m2 = -1.0; int e2 = 0;
        #pragma unroll
        for (int e = 0; e < E_; ++e) if (e != e1 && p[e] > m2) { m2 = p[e]; e2 = e; }
        float c1 = (float)(m1 / (m1 + m2)), c2 = (float)(m2 / (m1 + m2));
        #pragma unroll
        for (int e = 0; e < E_; ++e)
            combine[t * E_ + e] = (e == e1) ? c1 : ((e == e2) ? c2 : 0.0f);
        int q1 = atomicAdd(&cnt[e1], 1); idx[e1 * T_ + q1] = t;
        int q2 = atomicAdd(&cnt[e2], 1); idx[e2 * T_ + q2] = t;
        atomicAdd(&fcnt[(t & 63) * E_ + e1], 1);
        #pragma unroll
        for (int e = 0; e < E_; ++e) atomicAdd(&psum[(t & 63) * E_ + e], (float)p[e]);
    }
}

__global__ void offsets_kernel(const int* __restrict__ cnt, int* __restrict__ off) {
    if (threadIdx.x == 0 && blockIdx.x == 0) {
        int o = 0;
        for (int e = 0; e < E_; ++e) { off[e] = o; o += ((cnt[e] + 127) >> 7) << 7; }
    }
}

// ---------------- GEMM1: h[slot, f] = gelu(x[tok] @ w1[e] + b1[e]), bf16 out ----------------
// m97 structure: global_load_lds(16B) staging into linear LDS [128][64], 2-barrier K loop.
__global__ __launch_bounds__(256) void gemm1_kernel(
    const u16* __restrict__ xb, const u16* __restrict__ w1t,
    const float* __restrict__ b1, const int* __restrict__ idxAll,
    const int* __restrict__ cntAll, const int* __restrict__ off,
    u16* __restrict__ h)
{
    const int e = blockIdx.z;
    const int cnt = cntAll[e];
    const int tm = blockIdx.y, tn = blockIdx.x;
    if (tm * 128 >= cnt) return;
    const int base = off[e];
    const int* idx_e = idxAll + e * T_;
    const u16* Bsrc = w1t + (size_t)e * D_ * F_;   // [F][D] bf16

    __shared__ __align__(16) u16 As[128 * 64];
    __shared__ __align__(16) u16 Bs[128 * 64];
    const int tid = threadIdx.x;
    const int l = tid & 63, wid = tid >> 6;
    const int wm = (wid >> 1) * 64, wn = (wid & 1) * 64;
    const int lr = l & 15, lg = l >> 4;

    f32x4 acc[4][4];
    #pragma unroll
    for (int mi = 0; mi < 4; ++mi)
        #pragma unroll
        for (int ni = 0; ni < 4; ++ni)
            acc[mi][ni] = (f32x4){0.f, 0.f, 0.f, 0.f};

    // staging map: chunk c = wid*4+i covers LDS rows c*8..c*8+8; lane l -> row c*8+l/8, 16B at (l%8)*16
    const int kc = (l & 7) * 8;
    const u16 *aptr[4], *bptr[4];
    u16 *alds[4], *blds[4];
    #pragma unroll
    for (int i = 0; i < 4; ++i) {
        int row = wid * 32 + i * 8 + (l >> 3);
        int r = tm * 128 + row;
        int tok = (r < cnt) ? idx_e[r] : idx_e[0];
        aptr[i] = xb + (size_t)tok * D_ + kc;
        bptr[i] = Bsrc + (size_t)(tn * 128 + row) * D_ + kc;
        alds[i] = As + (wid * 4 + i) * 512;
        blds[i] = Bs + (wid * 4 + i) * 512;
    }

    for (int k0 = 0; k0 < D_; k0 += 64) {
        #pragma unroll
        for (int i = 0; i < 4; ++i) GLOAD16(aptr[i] + k0, alds[i]);
        #pragma unroll
        for (int i = 0; i < 4; ++i) GLOAD16(bptr[i] + k0, blds[i]);
        __syncthreads();   // compiler emits vmcnt(0) drain before barrier
        #pragma unroll
        for (int kb = 0; kb < 2; ++kb) {
            bf16x8 af[4], bfv[4];
            #pragma unroll
            for (int mi = 0; mi < 4; ++mi)
                af[mi] = *(const bf16x8*)(As + (wm + mi * 16 + lr) * 64 + kb * 32 + lg * 8);
            #pragma unroll
            for (int ni = 0; ni < 4; ++ni)
                bfv[ni] = *(const bf16x8*)(Bs + (wn + ni * 16 + lr) * 64 + kb * 32 + lg * 8);
            #pragma unroll
            for (int mi = 0; mi < 4; ++mi)
                #pragma unroll
                for (int ni = 0; ni < 4; ++ni)
                    acc[mi][ni] = __builtin_amdgcn_mfma_f32_16x16x32_bf16(af[mi], bfv[ni], acc[mi][ni], 0, 0, 0);
        }
        __syncthreads();
    }

    const float* b1e = b1 + e * F_;
    #pragma unroll
    for (int mi = 0; mi < 4; ++mi) {
        int rb = wm + mi * 16 + lg * 4;
        #pragma unroll
        for (int ni = 0; ni < 4; ++ni) {
            int f = tn * 128 + wn + ni * 16 + lr;
            float bias = b1e[f];
            #pragma unroll
            for (int j = 0; j < 4; ++j) {
                int slot = base + tm * 128 + rb + j;
                h[(size_t)slot * F_ + f] = f2b(gelu_f(acc[mi][ni][j] + bias));
            }
        }
    }
}

// ---------------- GEMM2: out[tok, d] += combine * (h @ w2[e] + b2[e]) ----------------
__global__ __launch_bounds__(256) void gemm2_kernel(
    const u16* __restrict__ h, const u16* __restrict__ w2t,
    const float* __restrict__ b2, const float* __restrict__ combine,
    const int* __restrict__ idxAll, const int* __restrict__ cntAll,
    const int* __restrict__ off, float* __restrict__ out)
{
    const int e = blockIdx.z;
    const int cnt = cntAll[e];
    const int tm = blockIdx.y, tn = blockIdx.x;
    if (tm * 128 >= cnt) return;
    const int base = off[e];
    const int* idx_e = idxAll + e * T_;
    const u16* Bsrc = w2t + (size_t)e * F_ * D_;   // [D][F] bf16

    __shared__ __align__(16) u16 As[128 * 64];
    __shared__ __align__(16) u16 Bs[128 * 64];
    const int tid = threadIdx.x;
    const int l = tid & 63, wid = tid >> 6;
    const int wm = (wid >> 1) * 64, wn = (wid & 1) * 64;
    const int lr = l & 15, lg = l >> 4;

    f32x4 acc[4][4];
    #pragma unroll
    for (int mi = 0; mi < 4; ++mi)
        #pragma unroll
        for (int ni = 0; ni < 4; ++ni)
            acc[mi][ni] = (f32x4){0.f, 0.f, 0.f, 0.f};

    const int kc = (l & 7) * 8;
    const u16 *aptr[4], *bptr[4];
    u16 *alds[4], *blds[4];
    #pragma unroll
    for (int i = 0; i < 4; ++i) {
        int row = wid * 32 + i * 8 + (l >> 3);
        aptr[i] = h + (size_t)(base + tm * 128 + row) * F_ + kc;
        bptr[i] = Bsrc + (size_t)(tn * 128 + row) * F_ + kc;
        alds[i] = As + (wid * 4 + i) * 512;
        blds[i] = Bs + (wid * 4 + i) * 512;
    }

    for (int k0 = 0; k0 < F_; k0 += 64) {
        #pragma unroll
        for (int i = 0; i < 4; ++i) GLOAD16(aptr[i] + k0, alds[i]);
        #pragma unroll
        for (int i = 0; i < 4; ++i) GLOAD16(bptr[i] + k0, blds[i]);
        __syncthreads();
        #pragma unroll
        for (int kb = 0; kb < 2; ++kb) {
            bf16x8 af[4], bfv[4];
            #pragma unroll
            for (int mi = 0; mi < 4; ++mi)
                af[mi] = *(const bf16x8*)(As + (wm + mi * 16 + lr) * 64 + kb * 32 + lg * 8);
            #pragma unroll
            for (int ni = 0; ni < 4; ++ni)
                bfv[ni] = *(const bf16x8*)(Bs + (wn + ni * 16 + lr) * 64 + kb * 32 + lg * 8);
            #pragma unroll
            for (int mi = 0; mi < 4; ++mi)
                #pragma unroll
                for (int ni = 0; ni < 4; ++ni)
                    acc[mi][ni] = __builtin_amdgcn_mfma_f32_16x16x32_bf16(af[mi], bfv[ni], acc[mi][ni], 0, 0, 0);
        }
        __syncthreads();
    }

    const float* b2e = b2 + e * D_;
    #pragma unroll
    for (int mi = 0; mi < 4; ++mi) {
        #pragma unroll
        for (int j = 0; j < 4; ++j) {
            int r = tm * 128 + wm + mi * 16 + lg * 4 + j;
            if (r < cnt) {
                int t = idx_e[r];
                float cw = combine[t * E_ + e];
                float* orow = out + (size_t)t * D_;
                #pragma unroll
                for (int ni = 0; ni < 4; ++ni) {
                    int d = tn * 128 + wn + ni * 16 + lr;
                    atomicAdd(&orow[d], cw * (acc[mi][ni][j] + b2e[d]));
                }
            }
        }
    }
}

__global__ void loss_kernel(const int* __restrict__ fcnt, const float* __restrict__ psum,
                            float* __restrict__ dst) {
    if (threadIdx.x == 0 && blockIdx.x == 0) {
        float loss = 0.f;
        for (int e = 0; e < E_; ++e) {
            float fs = 0.f, Ps = 0.f;
            for (int s = 0; s < 64; ++s) { fs += (float)fcnt[s * E_ + e]; Ps += psum[s * E_ + e]; }
            loss += (fs / (float)T_) * (Ps / (float)T_);
        }
        *dst = LBW_ * (float)E_ * loss;
    }
}

__global__ void sentinel_kernel(float* __restrict__ dst) {
    if (threadIdx.x == 0) dst[0] = -12345.0f;
}

extern "C" void kernel_launch(void* const* d_in, const int* in_sizes, int n_in,
                              void* d_out, int out_size, void* d_ws, size_t ws_size,
                              hipStream_t stream)
{
    const float* x  = (const float*)d_in[0];
    const float* ew = (const float*)d_in[1];
    const float* gw = (const float*)d_in[2];
    const float* gb = (const float*)d_in[3];
    const float* w1 = (const float*)d_in[4];
    const float* b1 = (const float*)d_in[5];
    const float* w2 = (const float*)d_in[6];
    const float* b2 = (const float*)d_in[7];
    float* out = (float*)d_out;

    char* ws = (char*)d_ws;
    size_t o = 0;
    u16* w1t = (u16*)(ws + o); o += (size_t)E_ * D_ * F_ * 2;
    u16* w2t = (u16*)(ws + o); o += (size_t)E_ * F_ * D_ * 2;
    u16* xb  = (u16*)(ws + o); o += (size_t)T_ * D_ * 2;
    u16* h   = (u16*)(ws + o); o += (size_t)HROWS_ * F_ * 2;
    float* combine = (float*)(ws + o); o += (size_t)T_ * E_ * 4;
    int* idx = (int*)(ws + o); o += (size_t)E_ * T_ * 4;
    size_t zoff = o;
    int* cnt   = (int*)(ws + o); o += 128;
    int* fcnt  = (int*)(ws + o); o += 64 * E_ * 4;
    float* psum = (float*)(ws + o); o += 64 * E_ * 4;
    int* off   = (int*)(ws + o); o += 128;
    const size_t ws_needed = o;

    if (ws_size < ws_needed) {
        hipMemsetAsync(d_out, 0, (size_t)out_size * sizeof(float), stream);
        sentinel_kernel<<<1, 64, 0, stream>>>(out + (size_t)out_size - 1);
        return;
    }

    hipMemsetAsync(ws + zoff, 0, ws_needed - zoff, stream);
    hipMemsetAsync(d_out, 0, (size_t)out_size * sizeof(float), stream);

    cvt_T_kernel<<<dim3(F_ / 64, D_ / 64, E_), 256, 0, stream>>>(w1, w1t, D_, F_);
    cvt_T_kernel<<<dim3(D_ / 64, F_ / 64, E_), 256, 0, stream>>>(w2, w2t, F_, D_);
    gate_kernel<<<T_, 64, 0, stream>>>(x, ew, gw, gb, xb, combine, idx, cnt, fcnt, psum);
    offsets_kernel<<<1, 64, 0, stream>>>(cnt, off);
    gemm1_kernel<<<dim3(F_ / 128, T_ / 128, E_), 256, 0, stream>>>(xb, w1t, b1, idx, cnt, off, h);
    gemm2_kernel<<<dim3(D_ / 128, T_ / 128, E_), 256, 0, stream>>>(h, w2t, b2, combine, idx, cnt, off, out);
    loss_kernel<<<1, 64, 0, stream>>>(fcnt, psum, out + (size_t)out_size - 1);
}

// Round 3
// 857.422 us; speedup vs baseline: 1.1324x; 1.1322x over previous
//
#include <hip/hip_runtime.h>
#include <math.h>

#define B_ 4
#define S_ 2048
#define D_ 1024
#define F_ 4096
#define E_ 8
#define T_ 8192
#define LBW_ 0.01f
#define HROWS_ 17408  // sum of per-expert 128-padded counts <= 16384 + 8*127, rounded up

#define BUFB 49152    // bytes per LDS buffer: A-tile 256x64x2 (32768) + B-tile 128x64x2 (16384)
#define ABYTES 32768

typedef unsigned short u16;
typedef __attribute__((ext_vector_type(8))) short bf16x8;
typedef __attribute__((ext_vector_type(4))) float f32x4;

// async global->LDS, 16B per lane; LDS dest = wave-uniform base + lane*16
#define GLOAD16(gp, lp) __builtin_amdgcn_global_load_lds( \
    (const __attribute__((address_space(1))) void*)(gp),  \
    (__attribute__((address_space(3))) void*)(lp), 16, 0, 0)

__device__ __forceinline__ u16 f2b(float f) {
    unsigned u = __float_as_uint(f);
    u = (u + 0x7FFFu + ((u >> 16) & 1u)) >> 16;   // RNE f32 -> bf16
    return (u16)u;
}
__device__ __forceinline__ float gelu_f(float v) {
    return 0.5f * v * (1.0f + erff(v * 0.70710678118654752440f));
}

// ------- per-expert transpose + convert: src (R x C f32, row-major) -> dst (C x R bf16) -------
__global__ __launch_bounds__(256) void cvt_T_kernel(const float* __restrict__ src,
                                                    u16* __restrict__ dst, int R, int C) {
    __shared__ u16 t[64][72];
    const int e = blockIdx.z;
    const float* s = src + (size_t)e * R * C;
    u16* d = dst + (size_t)e * R * C;
    const int r0 = blockIdx.y * 64, c0 = blockIdx.x * 64;
    const int tid = threadIdx.x;
    {
        int rr = tid >> 2, cq = (tid & 3) * 16;
        #pragma unroll
        for (int j = 0; j < 16; j += 4) {
            float4 v = *(const float4*)(s + (size_t)(r0 + rr) * C + c0 + cq + j);
            t[cq + j + 0][rr] = f2b(v.x);
            t[cq + j + 1][rr] = f2b(v.y);
            t[cq + j + 2][rr] = f2b(v.z);
            t[cq + j + 3][rr] = f2b(v.w);
        }
    }
    __syncthreads();
    {
        int cr = tid >> 2, rq = (tid & 3) * 16;
        #pragma unroll
        for (int j = 0; j < 16; j += 8) {
            int4 pk; u16* pw = (u16*)&pk;
            #pragma unroll
            for (int jj = 0; jj < 8; ++jj) pw[jj] = t[cr][rq + j + jj];
            *(int4*)(d + (size_t)(c0 + cr) * R + r0 + rq + j) = pk;
        }
    }
}

// ------- gate: logits (f64), softmax, top-2, routing lists, loss partials; also x->bf16 -------
__global__ __launch_bounds__(64) void gate_kernel(
    const float* __restrict__ x, const float* __restrict__ ew,
    const float* __restrict__ gw, const float* __restrict__ gb,
    u16* __restrict__ xb,
    float* __restrict__ combine, int* __restrict__ idx, int* __restrict__ cnt,
    int* __restrict__ fcnt, float* __restrict__ psum)
{
    const int t = blockIdx.x, l = threadIdx.x;
    const float* xr = x + (size_t)t * D_;
    double acc[E_];
    #pragma unroll
    for (int e = 0; e < E_; ++e) acc[e] = 0.0;
    u16 xw[16];
    #pragma unroll
    for (int kk = 0; kk < 16; kk += 4) {
        float4 xv = *(const float4*)(xr + l * 16 + kk);
        float xs[4] = {xv.x, xv.y, xv.z, xv.w};
        #pragma unroll
        for (int j = 0; j < 4; ++j) {
            xw[kk + j] = f2b(xs[j]);
            const float* gr = gw + (size_t)(l * 16 + kk + j) * E_;
            float4 g0 = *(const float4*)(gr);
            float4 g1 = *(const float4*)(gr + 4);
            acc[0] += (double)xs[j] * g0.x;  acc[1] += (double)xs[j] * g0.y;
            acc[2] += (double)xs[j] * g0.z;  acc[3] += (double)xs[j] * g0.w;
            acc[4] += (double)xs[j] * g1.x;  acc[5] += (double)xs[j] * g1.y;
            acc[6] += (double)xs[j] * g1.z;  acc[7] += (double)xs[j] * g1.w;
        }
    }
    *(int4*)(xb + (size_t)t * D_ + l * 16)     = *(int4*)(xw);
    *(int4*)(xb + (size_t)t * D_ + l * 16 + 8) = *(int4*)(xw + 8);
    #pragma unroll
    for (int e = 0; e < E_; ++e) {
        #pragma unroll
        for (int m = 32; m > 0; m >>= 1) acc[e] += __shfl_xor(acc[e], m);
    }
    if (l == 0) {
        const int b = t / S_;
        double p[E_]; double mx = -1e300;
        #pragma unroll
        for (int e = 0; e < E_; ++e) {
            p[e] = acc[e] + (double)gb[e] + (double)ew[b * E_ + e];
            mx = fmax(mx, p[e]);
        }
        double s = 0.0;
        #pragma unroll
        for (int e = 0; e < E_; ++e) { p[e] = exp(p[e] - mx); s += p[e]; }
        double inv = 1.0 / s;
        #pragma unroll
        for (int e = 0; e < E_; ++e) p[e] *= inv;
        double m1 = -1.0; int e1 = 0;
        #pragma unroll
        for (int e = 0; e < E_; ++e) if (p[e] > m1) { m1 = p[e]; e1 = e; }
        double m2 = -1.0; int e2 = 0;
        #pragma unroll
        for (int e = 0; e < E_; ++e) if (e != e1 && p[e] > m2) { m2 = p[e]; e2 = e; }
        float c1 = (float)(m1 / (m1 + m2)), c2 = (float)(m2 / (m1 + m2));
        #pragma unroll
        for (int e = 0; e < E_; ++e)
            combine[t * E_ + e] = (e == e1) ? c1 : ((e == e2) ? c2 : 0.0f);
        int q1 = atomicAdd(&cnt[e1], 1); idx[e1 * T_ + q1] = t;
        int q2 = atomicAdd(&cnt[e2], 1); idx[e2 * T_ + q2] = t;
        atomicAdd(&fcnt[(t & 63) * E_ + e1], 1);
        #pragma unroll
        for (int e = 0; e < E_; ++e) atomicAdd(&psum[(t & 63) * E_ + e], (float)p[e]);
    }
}

__global__ void offsets_kernel(const int* __restrict__ cnt, int* __restrict__ off) {
    if (threadIdx.x == 0 && blockIdx.x == 0) {
        int o = 0;
        for (int e = 0; e < E_; ++e) { off[e] = o; o += ((cnt[e] + 127) >> 7) << 7; }
    }
}

// ---------------- fused-expert GEMM, 256x128 tile, BK=64, triple-buffered counted-vmcnt ----------
// IS_G1: A = xb gathered rows (K=1024), out = h (gelu+b1).  !IS_G1: A = h rows (K=4096), out += atomic.
template<int NT, bool IS_G1>
__global__ __launch_bounds__(512, 2) void moe_gemm_kernel(
    const u16* __restrict__ Aglob, const u16* __restrict__ Wt,
    const float* __restrict__ bias, const float* __restrict__ combine,
    const int* __restrict__ idxAll, const int* __restrict__ cntAll,
    const int* __restrict__ off,
    u16* __restrict__ hOut, float* __restrict__ out)
{
    constexpr int KD = NT * 64;
    const int e = blockIdx.z;
    const int cnt = cntAll[e];
    const int tm = blockIdx.y, tn = blockIdx.x;
    if (tm * 256 >= cnt) return;
    const int base = off[e];
    const int* idx_e = idxAll + e * T_;
    const u16* Bsrc = Wt + (size_t)e * ((size_t)D_ * F_);

    __shared__ __align__(16) char ldsr[3 * BUFB];

    const int tid = threadIdx.x;
    const int l = tid & 63, wid = tid >> 6;
    const int wm = (wid >> 1) * 64, wn = (wid & 1) * 64;   // wave tile 64x64 within 256x128
    const int lr = l & 15, lg = l >> 4;

    // ---- stage source pointers (swizzled chunk: LDS chunk q of row r holds global chunk q^(r&7)) ----
    const int lrow8 = l >> 3;                 // row within 8-row slab = (r & 7)
    const int schunk = (l & 7) ^ lrow8;       // source chunk for this lane
    const u16* aptr[4]; const u16* bptr[2];
    #pragma unroll
    for (int i = 0; i < 4; ++i) {
        int row = (i * 8 + wid) * 8 + lrow8;            // 0..255
        int r = tm * 256 + row;
        if (IS_G1) {
            int tok = (r < cnt) ? idx_e[r] : idx_e[0];
            aptr[i] = Aglob + (size_t)tok * KD + schunk * 8;
        } else {
            int hr = base + r; if (hr > HROWS_ - 1) hr = HROWS_ - 1;   // clamp straddle reads
            aptr[i] = Aglob + (size_t)hr * KD + schunk * 8;
        }
    }
    #pragma unroll
    for (int j = 0; j < 2; ++j) {
        int row = (j * 8 + wid) * 8 + lrow8;            // 0..127
        bptr[j] = Bsrc + (size_t)(tn * 128 + row) * KD + schunk * 8;
    }

    f32x4 acc[4][4];
    #pragma unroll
    for (int mi = 0; mi < 4; ++mi)
        #pragma unroll
        for (int ni = 0; ni < 4; ++ni)
            acc[mi][ni] = (f32x4){0.f, 0.f, 0.f, 0.f};

    auto stage = [&](int sb, int kofe) {
        #pragma unroll
        for (int i = 0; i < 4; ++i)
            GLOAD16(aptr[i] + kofe, ldsr + sb + (i * 8 + wid) * 1024);
        #pragma unroll
        for (int j = 0; j < 2; ++j)
            GLOAD16(bptr[j] + kofe, ldsr + sb + ABYTES + (j * 8 + wid) * 1024);
    };

    // prologue: stage tiles 0 and 1; wait tile 0 only (tile 1's 6 loads stay in flight)
    stage(0, 0);
    stage(BUFB, 64);
    asm volatile("s_waitcnt vmcnt(6)" ::: "memory");
    __builtin_amdgcn_s_barrier();

    int cb = 0, sb2 = 2 * BUFB;
    int kofe = 128;
    for (int t = 0; t < NT; ++t) {
        // 1) frag ds_reads from current buffer (swizzled -> bank-uniform b128)
        bf16x8 af[8], bfv[8];
        #pragma unroll
        for (int kb = 0; kb < 2; ++kb)
            #pragma unroll
            for (int mi = 0; mi < 4; ++mi) {
                int row = wm + mi * 16 + lr;
                af[kb * 4 + mi] = *(const bf16x8*)(ldsr + cb + row * 128 + (((kb * 4 + lg) ^ (lr & 7)) * 16));
            }
        #pragma unroll
        for (int kb = 0; kb < 2; ++kb)
            #pragma unroll
            for (int ni = 0; ni < 4; ++ni) {
                int row = wn + ni * 16 + lr;
                bfv[kb * 4 + ni] = *(const bf16x8*)(ldsr + cb + ABYTES + row * 128 + (((kb * 4 + lg) ^ (lr & 7)) * 16));
            }
        // 2) issue stage of tile t+2 (completes by end of NEXT phase)
        if (t < NT - 2) { stage(sb2, kofe); kofe += 64; }
        // 3) MFMA cluster
        __builtin_amdgcn_s_setprio(1);
        #pragma unroll
        for (int kb = 0; kb < 2; ++kb)
            #pragma unroll
            for (int mi = 0; mi < 4; ++mi)
                #pragma unroll
                for (int ni = 0; ni < 4; ++ni)
                    acc[mi][ni] = __builtin_amdgcn_mfma_f32_16x16x32_bf16(af[kb * 4 + mi], bfv[kb * 4 + ni], acc[mi][ni], 0, 0, 0);
        __builtin_amdgcn_s_setprio(0);
        // 4) counted wait: drain tile t+1's 6 loads; keep t+2's 6 in flight across the barrier
        if (t < NT - 2)       { asm volatile("s_waitcnt vmcnt(6)" ::: "memory"); }
        else if (t == NT - 2) { asm volatile("s_waitcnt vmcnt(0)" ::: "memory"); }
        if (t < NT - 1) __builtin_amdgcn_s_barrier();
        cb += BUFB;  if (cb == 3 * BUFB)  cb = 0;
        sb2 += BUFB; if (sb2 == 3 * BUFB) sb2 = 0;
    }

    // ---- epilogue ----
    if (IS_G1) {
        const float* be = bias + e * F_;
        const int pad = ((cnt + 127) >> 7) << 7;
        #pragma unroll
        for (int mi = 0; mi < 4; ++mi) {
            #pragma unroll
            for (int j = 0; j < 4; ++j) {
                int rl = tm * 256 + wm + mi * 16 + lg * 4 + j;
                if (rl < pad) {
                    size_t srow = (size_t)(base + rl) * F_;
                    #pragma unroll
                    for (int ni = 0; ni < 4; ++ni) {
                        int f = tn * 128 + wn + ni * 16 + lr;
                        hOut[srow + f] = f2b(gelu_f(acc[mi][ni][j] + be[f]));
                    }
                }
            }
        }
    } else {
        const float* be = bias + e * D_;
        #pragma unroll
        for (int mi = 0; mi < 4; ++mi) {
            #pragma unroll
            for (int j = 0; j < 4; ++j) {
                int rl = tm * 256 + wm + mi * 16 + lg * 4 + j;
                if (rl < cnt) {
                    int tkn = idx_e[rl];
                    float cw = combine[tkn * E_ + e];
                    float* orow = out + (size_t)tkn * D_;
                    #pragma unroll
                    for (int ni = 0; ni < 4; ++ni) {
                        int d = tn * 128 + wn + ni * 16 + lr;
                        atomicAdd(&orow[d], cw * (acc[mi][ni][j] + be[d]));
                    }
                }
            }
        }
    }
}

__global__ void loss_kernel(const int* __restrict__ fcnt, const float* __restrict__ psum,
                            float* __restrict__ dst) {
    if (threadIdx.x == 0 && blockIdx.x == 0) {
        float loss = 0.f;
        for (int e = 0; e < E_; ++e) {
            float fs = 0.f, Ps = 0.f;
            for (int s = 0; s < 64; ++s) { fs += (float)fcnt[s * E_ + e]; Ps += psum[s * E_ + e]; }
            loss += (fs / (float)T_) * (Ps / (float)T_);
        }
        *dst = LBW_ * (float)E_ * loss;
    }
}

__global__ void sentinel_kernel(float* __restrict__ dst) {
    if (threadIdx.x == 0) dst[0] = -12345.0f;
}

extern "C" void kernel_launch(void* const* d_in, const int* in_sizes, int n_in,
                              void* d_out, int out_size, void* d_ws, size_t ws_size,
                              hipStream_t stream)
{
    const float* x  = (const float*)d_in[0];
    const float* ew = (const float*)d_in[1];
    const float* gw = (const float*)d_in[2];
    const float* gb = (const float*)d_in[3];
    const float* w1 = (const float*)d_in[4];
    const float* b1 = (const float*)d_in[5];
    const float* w2 = (const float*)d_in[6];
    const float* b2 = (const float*)d_in[7];
    float* out = (float*)d_out;

    char* ws = (char*)d_ws;
    size_t o = 0;
    u16* w1t = (u16*)(ws + o); o += (size_t)E_ * D_ * F_ * 2;
    u16* w2t = (u16*)(ws + o); o += (size_t)E_ * F_ * D_ * 2;
    u16* xb  = (u16*)(ws + o); o += (size_t)T_ * D_ * 2;
    u16* h   = (u16*)(ws + o); o += (size_t)HROWS_ * F_ * 2;
    float* combine = (float*)(ws + o); o += (size_t)T_ * E_ * 4;
    int* idx = (int*)(ws + o); o += (size_t)E_ * T_ * 4;
    size_t zoff = o;
    int* cnt   = (int*)(ws + o); o += 128;
    int* fcnt  = (int*)(ws + o); o += 64 * E_ * 4;
    float* psum = (float*)(ws + o); o += 64 * E_ * 4;
    int* off   = (int*)(ws + o); o += 128;
    const size_t ws_needed = o;

    if (ws_size < ws_needed) {
        hipMemsetAsync(d_out, 0, (size_t)out_size * sizeof(float), stream);
        sentinel_kernel<<<1, 64, 0, stream>>>(out + (size_t)out_size - 1);
        return;
    }

    hipMemsetAsync(ws + zoff, 0, ws_needed - zoff, stream);
    hipMemsetAsync(d_out, 0, (size_t)out_size * sizeof(float), stream);

    cvt_T_kernel<<<dim3(F_ / 64, D_ / 64, E_), 256, 0, stream>>>(w1, w1t, D_, F_);
    cvt_T_kernel<<<dim3(D_ / 64, F_ / 64, E_), 256, 0, stream>>>(w2, w2t, F_, D_);
    gate_kernel<<<T_, 64, 0, stream>>>(x, ew, gw, gb, xb, combine, idx, cnt, fcnt, psum);
    offsets_kernel<<<1, 64, 0, stream>>>(cnt, off);
    moe_gemm_kernel<16, true><<<dim3(F_ / 128, T_ / 256, E_), 512, 0, stream>>>(
        xb, w1t, b1, nullptr, idx, cnt, off, h, nullptr);
    moe_gemm_kernel<64, false><<<dim3(D_ / 128, T_ / 256, E_), 512, 0, stream>>>(
        h, w2t, b2, combine, idx, cnt, off, nullptr, out);
    loss_kernel<<<1, 64, 0, stream>>>(fcnt, psum, out + (size_t)out_size - 1);
}